// Round 7
// baseline (265.715 us; speedup 1.0000x reference)
//
#include <hip/hip_runtime.h>
#include <hip/hip_bf16.h>

#define N_NODES_C  100000
#define N_EDGES_C  1600000
#define IN_FEATS_C 128
#define OUT_FEATS_C 32
#define NEG_SLOPE_C 0.2f

typedef __attribute__((ext_vector_type(8))) short short8;
typedef __attribute__((ext_vector_type(4))) float f32x4;

// Static device scratch — no assumption about ws_size.
__device__ __hip_bfloat16 g_zb[N_NODES_C * OUT_FEATS_C];  // bf16 z copy: 64B/row
__device__ float  g_el[N_NODES_C];
__device__ float  g_er[N_NODES_C];
__device__ int    g_head[N_NODES_C];    // linked-list head per dst node
__device__ int    g_deg[N_NODES_C];     // per-dst degree
__device__ int    g_off[N_NODES_C + 1]; // CSR offsets
__device__ int2   g_ns[N_EDGES_C];      // packed {next, src} per edge
__device__ int    g_csr[N_EDGES_C];     // flattened src lists (by dst)
__device__ int    g_bsum[512];
__device__ int    g_btop[512];
__device__ short8 g_wf_hi[2][4][64];    // W MFMA B-fragments (bf16 hi)
__device__ short8 g_wf_lo[2][4][64];    // ... lo part (hi+lo split ~ f32 accuracy)

static __device__ __forceinline__ unsigned short f2bf(float x) {
    unsigned int u = __float_as_uint(x);
    unsigned int r = (u + 0x7FFFu + ((u >> 16) & 1u)) >> 16;
    return (unsigned short)r;
}
static __device__ __forceinline__ float bf2f(unsigned short h) {
    return __uint_as_float(((unsigned int)h) << 16);
}

// ---------------- Kernel 0: one-shot W -> MFMA B-fragment build ----------------
__global__ __launch_bounds__(256) void k_wt(const float* __restrict__ W)
{
    int i = blockIdx.x * 256 + threadIdx.x;      // 0..511
    if (i >= 512) return;
    int lane = i & 63;
    int kt   = (i >> 6) & 3;
    int nt   = i >> 8;
    int row  = nt * 16 + (lane & 15);
    const float* p = W + (size_t)row * IN_FEATS_C + kt * 32 + (lane >> 4) * 8;
    float4 x0 = *(const float4*)(p);
    float4 x1 = *(const float4*)(p + 4);
    float xs[8] = {x0.x, x0.y, x0.z, x0.w, x1.x, x1.y, x1.z, x1.w};
    short8 hi, lo;
#pragma unroll
    for (int j = 0; j < 8; ++j) {
        unsigned short hb = f2bf(xs[j]);
        hi[j] = (short)hb;
        lo[j] = (short)f2bf(xs[j] - bf2f(hb));
    }
    g_wf_hi[nt][kt][lane] = hi;
    g_wf_lo[nt][kt][lane] = lo;
}

// ---------------- Kernel 1: MFMA projection ----------------
// One wave per 16-node tile; 3 MFMAs per (ktile,ntile) via hi/lo split.
// Epilogue: bf16 z store, el/er reductions, head=-1, deg=0.
__global__ __launch_bounds__(256) void k_project(const float* __restrict__ h,
                                                 const float* __restrict__ a,
                                                 int n_nodes)
{
    int tile = (blockIdx.x * 256 + threadIdx.x) >> 6;
    int l    = threadIdx.x & 63;
    int ntiles = (n_nodes + 15) / 16;
    if (tile >= ntiles) return;
    int r16 = l & 15;
    int g   = l >> 4;

    const float* hrow = h + (size_t)(tile * 16 + r16) * IN_FEATS_C + g * 8;
    f32x4 acc0 = {0.f, 0.f, 0.f, 0.f};
    f32x4 acc1 = {0.f, 0.f, 0.f, 0.f};

#pragma unroll
    for (int kt = 0; kt < 4; ++kt) {
        float4 x0 = *(const float4*)(hrow + kt * 32);
        float4 x1 = *(const float4*)(hrow + kt * 32 + 4);
        float xs[8] = {x0.x, x0.y, x0.z, x0.w, x1.x, x1.y, x1.z, x1.w};
        short8 ahi, alo;
#pragma unroll
        for (int j = 0; j < 8; ++j) {
            unsigned short hb = f2bf(xs[j]);
            ahi[j] = (short)hb;
            alo[j] = (short)f2bf(xs[j] - bf2f(hb));
        }
        short8 bh0 = g_wf_hi[0][kt][l], bl0 = g_wf_lo[0][kt][l];
        short8 bh1 = g_wf_hi[1][kt][l], bl1 = g_wf_lo[1][kt][l];
        acc0 = __builtin_amdgcn_mfma_f32_16x16x32_bf16(ahi, bh0, acc0, 0, 0, 0);
        acc0 = __builtin_amdgcn_mfma_f32_16x16x32_bf16(alo, bh0, acc0, 0, 0, 0);
        acc0 = __builtin_amdgcn_mfma_f32_16x16x32_bf16(ahi, bl0, acc0, 0, 0, 0);
        acc1 = __builtin_amdgcn_mfma_f32_16x16x32_bf16(ahi, bh1, acc1, 0, 0, 0);
        acc1 = __builtin_amdgcn_mfma_f32_16x16x32_bf16(alo, bh1, acc1, 0, 0, 0);
        acc1 = __builtin_amdgcn_mfma_f32_16x16x32_bf16(ahi, bl1, acc1, 0, 0, 0);
    }

    float al0 = a[r16], al1 = a[16 + r16];
    float ar0 = a[32 + r16], ar1 = a[48 + r16];
    float elp[4], erp[4];
    unsigned short* zb = (unsigned short*)g_zb;
#pragma unroll
    for (int r = 0; r < 4; ++r) {
        float z0 = acc0[r], z1 = acc1[r];
        int node = tile * 16 + g * 4 + r;
        zb[(size_t)node * OUT_FEATS_C + r16]      = f2bf(z0);
        zb[(size_t)node * OUT_FEATS_C + 16 + r16] = f2bf(z1);
        elp[r] = z0 * al0 + z1 * al1;
        erp[r] = z0 * ar0 + z1 * ar1;
    }
#pragma unroll
    for (int m = 1; m <= 8; m <<= 1) {
#pragma unroll
        for (int r = 0; r < 4; ++r) {
            elp[r] += __shfl_xor(elp[r], m, 64);
            erp[r] += __shfl_xor(erp[r], m, 64);
        }
    }
    int nodeb = tile * 16 + g * 4;
    if (r16 == 0) {
#pragma unroll
        for (int r = 0; r < 4; ++r) g_el[nodeb + r] = elp[r];
    } else if (r16 == 1) {
#pragma unroll
        for (int r = 0; r < 4; ++r) g_er[nodeb + r] = erp[r];
    } else if (r16 == 2) {
#pragma unroll
        for (int r = 0; r < 4; ++r) g_head[nodeb + r] = -1;  // re-init every call
    } else if (r16 == 3) {
#pragma unroll
        for (int r = 0; r < 4; ++r) g_deg[nodeb + r] = 0;    // re-init every call
    }
}

// ---------------- Kernel 2: linked-list build + degree count ----------------
__global__ __launch_bounds__(256) void k_link(const int* __restrict__ src,
                                              const int* __restrict__ dst, int n_edges)
{
    int e = blockIdx.x * blockDim.x + threadIdx.x;
    if (e < n_edges) {
        int d = dst[e];
        int nxt = atomicExch(&g_head[d], e);
        atomicAdd(&g_deg[d], 1);
        g_ns[e] = make_int2(nxt, src[e]);
    }
}

// ---------------- Scan phase 1: per-256-block exclusive scan of deg ----------------
__global__ __launch_bounds__(256) void k_scan1(int n)
{
    __shared__ int lds[256];
    int i = blockIdx.x * 256 + threadIdx.x;
    int v = (i < n) ? g_deg[i] : 0;
    int val = v;
    lds[threadIdx.x] = v;
    __syncthreads();
    for (int off = 1; off < 256; off <<= 1) {
        int add = (threadIdx.x >= off) ? lds[threadIdx.x - off] : 0;
        __syncthreads();
        val += add;
        lds[threadIdx.x] = val;
        __syncthreads();
    }
    if (i < n) g_off[i] = val - v;
    if (threadIdx.x == 255) g_bsum[blockIdx.x] = val;
}

// ---------------- Scan phase 2: scan of block sums (<=512 blocks) ----------------
__global__ __launch_bounds__(512) void k_scan2(int nblocks)
{
    __shared__ int lds[512];
    int i = threadIdx.x;
    int v = (i < nblocks) ? g_bsum[i] : 0;
    int val = v;
    lds[i] = v;
    __syncthreads();
    for (int off = 1; off < 512; off <<= 1) {
        int add = (i >= off) ? lds[i - off] : 0;
        __syncthreads();
        val += add;
        lds[i] = val;
        __syncthreads();
    }
    g_btop[i] = val - v;
}

// ---------------- Scan phase 3: add block bases ----------------
__global__ __launch_bounds__(256) void k_scan3(int n, int n_edges)
{
    int i = blockIdx.x * 256 + threadIdx.x;
    if (i < n) g_off[i] += g_btop[i >> 8];
    if (i == 0) g_off[n] = n_edges;
}

// ---------------- Kernel: flatten chains to CSR ----------------
// ONE THREAD PER NODE: 100k independent chain walks in parallel (64/wave),
// vs k_gather's old 1-chain-per-32-lanes. No atomics; consecutive lanes own
// consecutive nodes so csr writes from a wave share lines (L2-merged).
__global__ __launch_bounds__(256) void k_flat(int n_nodes)
{
    int n = blockIdx.x * 256 + threadIdx.x;
    if (n >= n_nodes) return;
    int pos = g_off[n];
    int j = g_head[n];
    while (j >= 0) {
        int2 ns = g_ns[j];
        g_csr[pos++] = ns.y;   // src
        j = ns.x;              // next
    }
}

// ---------------- Kernel: per-node gather over contiguous CSR ----------------
// 32 lanes per node (lane = feature). csr reads are group-uniform/sequential;
// z-row + el loads are INDEPENDENT (unroll x2, dual accumulators) -> high MLP
// instead of the old serial next-pointer chain.
__global__ __launch_bounds__(256) void k_gather(float* __restrict__ out, int n_nodes)
{
    int tid  = blockIdx.x * blockDim.x + threadIdx.x;
    int node = tid >> 5;
    int f    = tid & 31;
    if (node >= n_nodes) return;

    int start = g_off[node];
    int end   = g_off[node + 1];
    float er_d = g_er[node];
    const unsigned short* zb = (const unsigned short*)g_zb;

    float acc0 = 0.f, acc1 = 0.f, den0 = 0.f, den1 = 0.f;
    int j = start;
    for (; j + 2 <= end; j += 2) {
        int s0 = g_csr[j];
        int s1 = g_csr[j + 1];
        float x0 = g_el[s0] + er_d;
        float x1 = g_el[s1] + er_d;
        x0 = (x0 > 0.f) ? x0 : NEG_SLOPE_C * x0;
        x1 = (x1 > 0.f) ? x1 : NEG_SLOPE_C * x1;
        float e0 = __expf(x0);
        float e1 = __expf(x1);
        float z0 = bf2f(zb[(size_t)s0 * OUT_FEATS_C + f]);
        float z1 = bf2f(zb[(size_t)s1 * OUT_FEATS_C + f]);
        den0 += e0; den1 += e1;
        acc0 = fmaf(e0, z0, acc0);
        acc1 = fmaf(e1, z1, acc1);
    }
    if (j < end) {
        int s0 = g_csr[j];
        float x0 = g_el[s0] + er_d;
        x0 = (x0 > 0.f) ? x0 : NEG_SLOPE_C * x0;
        float e0 = __expf(x0);
        den0 += e0;
        acc0 = fmaf(e0, bf2f(zb[(size_t)s0 * OUT_FEATS_C + f]), acc0);
    }
    out[(size_t)node * OUT_FEATS_C + f] =
        (acc0 + acc1) / fmaxf(den0 + den1, 1e-16f);
}

extern "C" void kernel_launch(void* const* d_in, const int* in_sizes, int n_in,
                              void* d_out, int out_size, void* d_ws, size_t ws_size,
                              hipStream_t stream) {
    const float* h   = (const float*)d_in[0];
    const float* W   = (const float*)d_in[1];
    const float* a   = (const float*)d_in[2];
    const int*   src = (const int*)d_in[3];
    const int*   dst = (const int*)d_in[4];
    float* out = (float*)d_out;

    const int n_nodes = in_sizes[0] / IN_FEATS_C;   // 100000
    const int n_edges = in_sizes[3];                // 1600000
    const int nb_nodes = (n_nodes + 255) / 256;     // 391 (<=512 for k_scan2)

    // 0) W -> bf16 hi/lo MFMA fragments
    k_wt<<<2, 256, 0, stream>>>(W);
    // 1) MFMA projection (+ el/er + head/deg init)
    {
        int ntiles = (n_nodes + 15) / 16;
        int blocks = (ntiles + 3) / 4;
        k_project<<<blocks, 256, 0, stream>>>(h, a, n_nodes);
    }
    // 2) linked-list + degrees
    k_link<<<(n_edges + 255) / 256, 256, 0, stream>>>(src, dst, n_edges);
    // 3) offsets
    k_scan1<<<nb_nodes, 256, 0, stream>>>(n_nodes);
    k_scan2<<<1, 512, 0, stream>>>(nb_nodes);
    k_scan3<<<nb_nodes, 256, 0, stream>>>(n_nodes, n_edges);
    // 4) flatten chains to CSR (parallel chain walks)
    k_flat<<<nb_nodes, 256, 0, stream>>>(n_nodes);
    // 5) gather over contiguous CSR (independent loads, high MLP)
    k_gather<<<(n_nodes * 32 + 255) / 256, 256, 0, stream>>>(out, n_nodes);
}

// Round 8
// 225.042 us; speedup vs baseline: 1.1807x; 1.1807x over previous
//
#include <hip/hip_runtime.h>
#include <hip/hip_bf16.h>

#define N_NODES_C  100000
#define N_EDGES_C  1600000
#define IN_FEATS_C 128
#define OUT_FEATS_C 32
#define NEG_SLOPE_C 0.2f
#define NCH 8   // parallel chains per node (breaks the serial next-pointer walk)

typedef __attribute__((ext_vector_type(8))) short short8;
typedef __attribute__((ext_vector_type(4))) float f32x4;

// Static device scratch — no assumption about ws_size.
__device__ __hip_bfloat16 g_zb[N_NODES_C * OUT_FEATS_C];  // bf16 z copy: 64B/row
__device__ float  g_el[N_NODES_C];
__device__ float  g_er[N_NODES_C];
__device__ int    g_head[NCH][N_NODES_C];  // NCH linked-list heads per dst node
__device__ int2   g_ns[N_EDGES_C];         // packed {next, src} per edge
__device__ short8 g_wf_hi[2][4][64];       // W MFMA B-fragments (bf16 hi)
__device__ short8 g_wf_lo[2][4][64];       // ... lo part (hi+lo split ~ f32 accuracy)

static __device__ __forceinline__ unsigned short f2bf(float x) {
    unsigned int u = __float_as_uint(x);
    unsigned int r = (u + 0x7FFFu + ((u >> 16) & 1u)) >> 16;
    return (unsigned short)r;
}
static __device__ __forceinline__ float bf2f(unsigned short h) {
    return __uint_as_float(((unsigned int)h) << 16);
}

// ---------------- Kernel: init chain heads to -1 (coalesced, ~2us) ----------------
__global__ __launch_bounds__(256) void k_init(int n)
{
    int i = blockIdx.x * 256 + threadIdx.x;
    if (i < n) ((int*)g_head)[i] = -1;
}

// ---------------- Kernel 0: one-shot W -> MFMA B-fragment build ----------------
__global__ __launch_bounds__(256) void k_wt(const float* __restrict__ W)
{
    int i = blockIdx.x * 256 + threadIdx.x;      // 0..511
    if (i >= 512) return;
    int lane = i & 63;
    int kt   = (i >> 6) & 3;
    int nt   = i >> 8;
    int row  = nt * 16 + (lane & 15);
    const float* p = W + (size_t)row * IN_FEATS_C + kt * 32 + (lane >> 4) * 8;
    float4 x0 = *(const float4*)(p);
    float4 x1 = *(const float4*)(p + 4);
    float xs[8] = {x0.x, x0.y, x0.z, x0.w, x1.x, x1.y, x1.z, x1.w};
    short8 hi, lo;
#pragma unroll
    for (int j = 0; j < 8; ++j) {
        unsigned short hb = f2bf(xs[j]);
        hi[j] = (short)hb;
        lo[j] = (short)f2bf(xs[j] - bf2f(hb));
    }
    g_wf_hi[nt][kt][lane] = hi;
    g_wf_lo[nt][kt][lane] = lo;
}

// ---------------- Kernel 1: MFMA projection ----------------
// One wave per 16-node tile; 3 MFMAs per (ktile,ntile) via hi/lo split.
// Epilogue: bf16 z store + el/er via shfl reductions.
__global__ __launch_bounds__(256) void k_project(const float* __restrict__ h,
                                                 const float* __restrict__ a,
                                                 int n_nodes)
{
    int tile = (blockIdx.x * 256 + threadIdx.x) >> 6;
    int l    = threadIdx.x & 63;
    int ntiles = (n_nodes + 15) / 16;
    if (tile >= ntiles) return;
    int r16 = l & 15;
    int g   = l >> 4;

    const float* hrow = h + (size_t)(tile * 16 + r16) * IN_FEATS_C + g * 8;
    f32x4 acc0 = {0.f, 0.f, 0.f, 0.f};
    f32x4 acc1 = {0.f, 0.f, 0.f, 0.f};

#pragma unroll
    for (int kt = 0; kt < 4; ++kt) {
        float4 x0 = *(const float4*)(hrow + kt * 32);
        float4 x1 = *(const float4*)(hrow + kt * 32 + 4);
        float xs[8] = {x0.x, x0.y, x0.z, x0.w, x1.x, x1.y, x1.z, x1.w};
        short8 ahi, alo;
#pragma unroll
        for (int j = 0; j < 8; ++j) {
            unsigned short hb = f2bf(xs[j]);
            ahi[j] = (short)hb;
            alo[j] = (short)f2bf(xs[j] - bf2f(hb));
        }
        short8 bh0 = g_wf_hi[0][kt][l], bl0 = g_wf_lo[0][kt][l];
        short8 bh1 = g_wf_hi[1][kt][l], bl1 = g_wf_lo[1][kt][l];
        acc0 = __builtin_amdgcn_mfma_f32_16x16x32_bf16(ahi, bh0, acc0, 0, 0, 0);
        acc0 = __builtin_amdgcn_mfma_f32_16x16x32_bf16(alo, bh0, acc0, 0, 0, 0);
        acc0 = __builtin_amdgcn_mfma_f32_16x16x32_bf16(ahi, bl0, acc0, 0, 0, 0);
        acc1 = __builtin_amdgcn_mfma_f32_16x16x32_bf16(ahi, bh1, acc1, 0, 0, 0);
        acc1 = __builtin_amdgcn_mfma_f32_16x16x32_bf16(alo, bh1, acc1, 0, 0, 0);
        acc1 = __builtin_amdgcn_mfma_f32_16x16x32_bf16(ahi, bl1, acc1, 0, 0, 0);
    }

    float al0 = a[r16], al1 = a[16 + r16];
    float ar0 = a[32 + r16], ar1 = a[48 + r16];
    float elp[4], erp[4];
    unsigned short* zb = (unsigned short*)g_zb;
#pragma unroll
    for (int r = 0; r < 4; ++r) {
        float z0 = acc0[r], z1 = acc1[r];
        int node = tile * 16 + g * 4 + r;
        zb[(size_t)node * OUT_FEATS_C + r16]      = f2bf(z0);
        zb[(size_t)node * OUT_FEATS_C + 16 + r16] = f2bf(z1);
        elp[r] = z0 * al0 + z1 * al1;
        erp[r] = z0 * ar0 + z1 * ar1;
    }
#pragma unroll
    for (int m = 1; m <= 8; m <<= 1) {
#pragma unroll
        for (int r = 0; r < 4; ++r) {
            elp[r] += __shfl_xor(elp[r], m, 64);
            erp[r] += __shfl_xor(erp[r], m, 64);
        }
    }
    int nodeb = tile * 16 + g * 4;
    if (r16 == 0) {
#pragma unroll
        for (int r = 0; r < 4; ++r) g_el[nodeb + r] = elp[r];
    } else if (r16 == 1) {
#pragma unroll
        for (int r = 0; r < 4; ++r) g_er[nodeb + r] = erp[r];
    }
}

// ---------------- Kernel 2: multi-chain linked-list build ----------------
// ONE random atomic per edge (the proven-cheap build: R6 form). Edge e goes
// into chain e&7 of its dst so the gather has 8 independent load streams.
__global__ __launch_bounds__(256) void k_link(const int* __restrict__ src,
                                              const int* __restrict__ dst, int n_edges)
{
    int e = blockIdx.x * blockDim.x + threadIdx.x;
    if (e < n_edges) {
        int nxt = atomicExch(&g_head[e & (NCH - 1)][dst[e]], e);
        g_ns[e] = make_int2(nxt, src[e]);
    }
}

// ---------------- Kernel 3: gather via 8 concurrent chain walks ----------------
// 32 lanes per node (lane = feature). Per round: up to 8 independent g_ns
// lines + 8 el + 8 z-row lines in flight (avg chain length 16/8 = 2), vs the
// old single serial chain (MLP=1). Round count = max chain length (~4-5).
__global__ __launch_bounds__(256) void k_gather(float* __restrict__ out, int n_nodes)
{
    int tid  = blockIdx.x * blockDim.x + threadIdx.x;
    int node = tid >> 5;
    int f    = tid & 31;
    if (node >= n_nodes) return;

    float er_d = g_er[node];
    const unsigned short* zb = (const unsigned short*)g_zb;

    int j0 = g_head[0][node], j1 = g_head[1][node];
    int j2 = g_head[2][node], j3 = g_head[3][node];
    int j4 = g_head[4][node], j5 = g_head[5][node];
    int j6 = g_head[6][node], j7 = g_head[7][node];

    float acc = 0.f, den = 0.f;
    while ((j0 | j1 | j2 | j3 | j4 | j5 | j6 | j7) >= 0 ||
           j0 >= 0 || j1 >= 0 || j2 >= 0 || j3 >= 0 ||
           j4 >= 0 || j5 >= 0 || j6 >= 0 || j7 >= 0) {
        // issue all active next/src loads first (independent)
        int2 n0, n1, n2, n3, n4, n5, n6, n7;
        if (j0 >= 0) n0 = g_ns[j0];
        if (j1 >= 0) n1 = g_ns[j1];
        if (j2 >= 0) n2 = g_ns[j2];
        if (j3 >= 0) n3 = g_ns[j3];
        if (j4 >= 0) n4 = g_ns[j4];
        if (j5 >= 0) n5 = g_ns[j5];
        if (j6 >= 0) n6 = g_ns[j6];
        if (j7 >= 0) n7 = g_ns[j7];
#define STEP(jc, nc)                                                        \
        if (jc >= 0) {                                                      \
            int s = nc.y;                                                   \
            float x = g_el[s] + er_d;                                       \
            x = (x > 0.f) ? x : NEG_SLOPE_C * x;                            \
            float ex = __expf(x);                                           \
            den += ex;                                                      \
            acc = fmaf(ex, bf2f(zb[(size_t)s * OUT_FEATS_C + f]), acc);     \
            jc = nc.x;                                                      \
        }
        STEP(j0, n0) STEP(j1, n1) STEP(j2, n2) STEP(j3, n3)
        STEP(j4, n4) STEP(j5, n5) STEP(j6, n6) STEP(j7, n7)
#undef STEP
    }
    out[(size_t)node * OUT_FEATS_C + f] = acc / fmaxf(den, 1e-16f);
}

extern "C" void kernel_launch(void* const* d_in, const int* in_sizes, int n_in,
                              void* d_out, int out_size, void* d_ws, size_t ws_size,
                              hipStream_t stream) {
    const float* h   = (const float*)d_in[0];
    const float* W   = (const float*)d_in[1];
    const float* a   = (const float*)d_in[2];
    const int*   src = (const int*)d_in[3];
    const int*   dst = (const int*)d_in[4];
    float* out = (float*)d_out;

    const int n_nodes = in_sizes[0] / IN_FEATS_C;   // 100000
    const int n_edges = in_sizes[3];                // 1600000

    // 0) heads = -1 ; W -> bf16 hi/lo MFMA fragments
    k_init<<<(NCH * n_nodes + 255) / 256, 256, 0, stream>>>(NCH * n_nodes);
    k_wt<<<2, 256, 0, stream>>>(W);
    // 1) MFMA projection (+ el/er)
    {
        int ntiles = (n_nodes + 15) / 16;
        int blocks = (ntiles + 3) / 4;
        k_project<<<blocks, 256, 0, stream>>>(h, a, n_nodes);
    }
    // 2) multi-chain linked-list build (single atomic per edge)
    k_link<<<(n_edges + 255) / 256, 256, 0, stream>>>(src, dst, n_edges);
    // 3) gather: 8 concurrent chain walks per node
    k_gather<<<(n_nodes * 32 + 255) / 256, 256, 0, stream>>>(out, n_nodes);
}